// Round 5
// baseline (234.948 us; speedup 1.0000x reference)
//
#include <hip/hip_runtime.h>

// Multi-scale parabolic morphological closing — all-vertical-scan formulation.
// closing_k = erosion2d(dilation2d(x)) with separable parabolic SE, W_k = 4<<k,
// weight(d) = c*(4/W^2)*d^2. Separable dilation (and erosion) commutes across
// axes, so we run 4 vertical scans, each writing its output transposed:
//   X[h][w] -dilV-> T1[w][h] -dilW-> T2[h][w] -eroV-> T3[w][h] -eroW-> OUT[h][w]
// Per-candidate algebra: v -+ cw*(D-pp)^2 = (v -+ cw*D^2) +- (2cw*D)*pp -+ cw*pp^2.
// q=cw*D^2 and s=2cw*D advance by exact incremental recurrences (cw = c*2^-m,
// cw*int exact); the -+cw*pp^2 term is applied once in the epilogue. Window
// truncation (|d|<=W) is enforced by compile-time pp-subsets in the 7-tap
// head/tail phases; runtime-length middle phase has all 8 pp valid.
// R4 lesson: 4 unrolled bodies (~45KB) per kernel thrashed I-cache; this body
// is ~2KB and identical for every scale (runtime W). No LDS at all.

#define HH 256
#define WW 256
#define BC 32
#define NS 4
#define HW (HH * WW)
#define SLICE ((long)BC * HW)   // floats per packed all-image slice group

template <bool IS_MAX, bool CLAMP>
__device__ __forceinline__ void vscan_core(const float* __restrict__ img,
                                           float* __restrict__ outT,
                                           int W, float cw)
{
    const int x = threadIdx.x;        // fast-axis index (a full row load per u)
    const int h0 = blockIdx.y * 8;    // first of 8 owned slow-axis outputs
    const float PAD = IS_MAX ? -1e30f : 1e30f;
    const float tw = 2.0f * cw;

    // chain state at u=0  (D = -W):  q = cw*D^2, qs = cw*(2D+1), s = -+2cw*D
    float q  = cw * (float)(W * W);
    float qs = cw * (float)(1 - 2 * W);
    float s  = IS_MAX ? (-tw * (float)W) : (tw * (float)W);
    const float ss = IS_MAX ? tw : -tw;   // s step per u

    float acc[8];
#pragma unroll
    for (int pp = 0; pp < 8; ++pp) acc[pp] = PAD;

    const float* pb = img + x;
    const int hb = h0 - W;            // row at u=0

#define LOADU(u) (CLAMP ? ({ int h_ = hb + (u); int hc_ = min(max(h_, 0), HH - 1); \
                             float tv_ = pb[hc_ * WW]; (h_ == hc_) ? tv_ : PAD; }) \
                        : pb[(hb + (u)) * WW])

    // ---- head: u = 0..6, valid pp <= u (compile-time subset) ----
#pragma unroll
    for (int u = 0; u < 7; ++u) {
        const float v = LOADU(u);
        const float vp = IS_MAX ? v - q : v + q;
        const float sv = s;
#pragma unroll
        for (int pp = 0; pp < 8; ++pp)
            if (pp <= u) {
                const float c = fmaf(sv, (float)pp, vp);
                acc[pp] = IS_MAX ? fmaxf(acc[pp], c) : fminf(acc[pp], c);
            }
        q += qs; qs += tw; s += ss;
    }
    // ---- middle: u = 7..2W (all pp valid), pairs ----
    {
        int u = 7;
        const int nmid = (2 * W - 6) / 2;   // even for all W in {4,8,16,32}
        for (int it = 0; it < nmid; ++it, u += 2) {
            const float v0 = LOADU(u);
            const float v1 = LOADU(u + 1);
            const float vp0 = IS_MAX ? v0 - q : v0 + q;
            const float s0 = s;
            q += qs; qs += tw; s += ss;
            const float vp1 = IS_MAX ? v1 - q : v1 + q;
            const float s1 = s;
            q += qs; qs += tw; s += ss;
#pragma unroll
            for (int pp = 0; pp < 8; ++pp) {
                const float c0 = fmaf(s0, (float)pp, vp0);
                const float c1 = fmaf(s1, (float)pp, vp1);
                acc[pp] = IS_MAX ? fmaxf(acc[pp], fmaxf(c0, c1))
                                 : fminf(acc[pp], fminf(c0, c1));
            }
        }
    }
    // ---- tail: u = 2W+1..2W+7, valid pp >= ut (compile-time subset) ----
#pragma unroll
    for (int ut = 1; ut <= 7; ++ut) {
        const float v = LOADU(2 * W + ut);
        const float vp = IS_MAX ? v - q : v + q;
        const float sv = s;
#pragma unroll
        for (int pp = 0; pp < 8; ++pp)
            if (pp >= ut) {
                const float c = fmaf(sv, (float)pp, vp);
                acc[pp] = IS_MAX ? fmaxf(acc[pp], c) : fminf(acc[pp], c);
            }
        q += qs; qs += tw; s += ss;
    }
#undef LOADU

    // ---- epilogue: fold -+cw*pp^2, store transposed (8 contiguous floats) ----
    float res[8];
#pragma unroll
    for (int pp = 0; pp < 8; ++pp)
        res[pp] = IS_MAX ? fmaf(-cw, (float)(pp * pp), acc[pp])
                         : fmaf( cw, (float)(pp * pp), acc[pp]);
    float* op = outT + (long)x * WW + h0;
    *(float4*)(op)     = make_float4(res[0], res[1], res[2], res[3]);
    *(float4*)(op + 4) = make_float4(res[4], res[5], res[6], res[7]);
}

template <bool IS_MAX>
__global__ __launch_bounds__(256, 8) void vscan(const float* __restrict__ in,
                                                float* __restrict__ outT,
                                                const float* __restrict__ cptr,
                                                long in_ks, long in_zs,
                                                long out_ks, long out_zs, int kofs)
{
    const int k = kofs + blockIdx.x;       // scale (fastest grid dim: no slow tail)
    const int z = blockIdx.z;              // image
    const int W = 4 << k;
    const float cw = ldexpf(cptr[0], -(2 + 2 * k));   // c*4/W^2, exact pow2 scale
    const float* ip = in  + (long)k * in_ks + (long)z * in_zs;
    float* op       = outT + (long)k * out_ks + (long)z * out_zs;
    const int h0 = blockIdx.y * 8;
    if (h0 >= W && h0 + W + 7 <= HH - 1)
        vscan_core<IS_MAX, false>(ip, op, W, cw);     // interior: no clamp/select
    else
        vscan_core<IS_MAX, true >(ip, op, W, cw);
}

extern "C" void kernel_launch(void* const* d_in, const int* in_sizes, int n_in,
                              void* d_out, int out_size, void* d_ws, size_t ws_size,
                              hipStream_t stream)
{
    const float* x = (const float*)d_in[0];   // [4,8,256,256] fp32
    const float* c = (const float*)d_in[1];   // scalar se_coef
    float* out = (float*)d_out;               // [4,8,4,256,256] fp32
    float* ws  = (float*)d_ws;

    dim3 b(256);
    if (ws_size >= (size_t)(NS * SLICE) * sizeof(float)) {
        // 4 merged dispatches; packed intermediate layout [(k*BC+z)][256][256].
        // Rotation: X -> ws -> out(scratch) -> ws -> out(final). No dispatch
        // reads and writes the same buffer.
        dim3 g(NS, HH / 8, BC);
        vscan<true ><<<g, b, 0, stream>>>(x,   ws,  c, 0,     HW, SLICE, HW, 0);
        vscan<true ><<<g, b, 0, stream>>>(ws,  out, c, SLICE, HW, SLICE, HW, 0);
        vscan<false><<<g, b, 0, stream>>>(out, ws,  c, SLICE, HW, SLICE, HW, 0);
        vscan<false><<<g, b, 0, stream>>>(ws,  out, c, SLICE, HW, HW, (long)NS * HW, 0);
    } else {
        // per-scale fallback: needs 2 slices (16.8 MB) of ws
        float* wsA = ws;
        float* wsB = ws + SLICE;
        dim3 g(1, HH / 8, BC);
        for (int k = 0; k < NS; ++k) {
            vscan<true ><<<g, b, 0, stream>>>(x,   wsA, c, 0, HW, 0, HW, k);
            vscan<true ><<<g, b, 0, stream>>>(wsA, wsB, c, 0, HW, 0, HW, k);
            vscan<false><<<g, b, 0, stream>>>(wsB, wsA, c, 0, HW, 0, HW, k);
            vscan<false><<<g, b, 0, stream>>>(wsA, out, c, 0, HW, HW, (long)NS * HW, k);
        }
    }
}

// Round 6
// 182.954 us; speedup vs baseline: 1.2842x; 1.2842x over previous
//
#include <hip/hip_runtime.h>

// Multi-scale parabolic morphological closing — vertical-scan formulation with
// LDS-transposed coalesced output. closing_k = ero2d(dil2d(x)), W_k = 4<<k,
// weight(d) = c*(4/W^2)*d^2. Separable passes commute, so all 4 passes are
// vertical scans that write transposed:
//   X -dilV-> T1[w][h] -dilH-> T2[h][w] -eroV-> T3[w][h] -eroH-> OUT[h][w]
// Candidate algebra (exact chain recurrence, cw = c*2^-m):
//   v -+ cw*(D-pp)^2 = (v -+ cw*D^2) +- (2cw*D)*pp -+ cw*pp^2
// q=cw*D^2, s=2cw*D advance incrementally; -+cw*pp^2 folded in the epilogue.
// R5 lesson: transposed per-thread 32B stores = 64 lines/wave-store (16x write
// amplification) -> this version stages the 64x64 output tile in LDS and
// stores fully coalesced (4 lines/wave-store). Reads coalesced (wave = 64
// consecutive columns). One compact runtime-W body (~2KB): no I-cache thrash.

#define HH 256
#define FAST 256
#define BC 32
#define NS 4
#define HW (HH * FAST)
#define SLICE ((long)BC * HW)
#define LROW 68   // LDS row stride (floats): 16B-aligned rows, 64+4

// scan core: thread owns 8 consecutive slow-axis outputs at one fast-axis col.
template <bool IS_MAX, bool CLAMP>
__device__ __forceinline__ void scan_core(const float* __restrict__ img,
                                          int W, float cw, int x, int rowbase,
                                          float res[8])
{
    const float PAD = IS_MAX ? -1e30f : 1e30f;
    const float tw = 2.0f * cw;

    // chain state at u=0 (D = -W)
    float q  = cw * (float)(W * W);          // cw*D^2
    float qs = cw * (float)(1 - 2 * W);      // cw*(2D+1)
    float s  = IS_MAX ? (-tw * (float)W) : (tw * (float)W);   // -+2cw*D sign-folded
    const float ss = IS_MAX ? tw : -tw;

    float acc[8];
#pragma unroll
    for (int pp = 0; pp < 8; ++pp) acc[pp] = PAD;

    auto LOAD = [&](int u) -> float {
        if (!CLAMP) return img[x + (rowbase + u) * FAST];
        const int row = rowbase + u;
        const int rc = min(max(row, 0), HH - 1);       // always-safe address
        const float t = img[x + rc * FAST];
        return (row == rc) ? t : PAD;
    };

    // head: u = 0..6, tap valid for pp <= u  (pp >= u-2W always true, W >= 4)
#pragma unroll
    for (int u = 0; u < 7; ++u) {
        const float v = LOAD(u);
        const float vp = IS_MAX ? v - q : v + q;
        const float sv = s;
#pragma unroll
        for (int pp = 0; pp < 8; ++pp)
            if (pp <= u) {
                const float cnd = fmaf(sv, (float)pp, vp);
                acc[pp] = IS_MAX ? fmaxf(acc[pp], cnd) : fminf(acc[pp], cnd);
            }
        q += qs; qs += tw; s += ss;
    }
    // middle: u = 7..2W, all pp valid; process in pairs
    {
        const int nmid = W - 3;              // (2W-6)/2
        int u = 7;
        for (int it = 0; it < nmid; ++it, u += 2) {
            const float v0 = LOAD(u);
            const float v1 = LOAD(u + 1);
            const float vp0 = IS_MAX ? v0 - q : v0 + q;
            const float s0 = s;
            q += qs; qs += tw; s += ss;
            const float vp1 = IS_MAX ? v1 - q : v1 + q;
            const float s1 = s;
            q += qs; qs += tw; s += ss;
#pragma unroll
            for (int pp = 0; pp < 8; ++pp) {
                const float c0 = fmaf(s0, (float)pp, vp0);
                const float c1 = fmaf(s1, (float)pp, vp1);
                acc[pp] = IS_MAX ? fmaxf(acc[pp], fmaxf(c0, c1))
                                 : fminf(acc[pp], fminf(c0, c1));
            }
        }
    }
    // tail: u = 2W+1..2W+7, tap valid for pp >= ut
#pragma unroll
    for (int ut = 1; ut <= 7; ++ut) {
        const float v = LOAD(2 * W + ut);
        const float vp = IS_MAX ? v - q : v + q;
        const float sv = s;
#pragma unroll
        for (int pp = 0; pp < 8; ++pp)
            if (pp >= ut) {
                const float cnd = fmaf(sv, (float)pp, vp);
                acc[pp] = IS_MAX ? fmaxf(acc[pp], cnd) : fminf(acc[pp], cnd);
            }
        q += qs; qs += tw; s += ss;
    }
    // fold -+cw*pp^2
#pragma unroll
    for (int pp = 0; pp < 8; ++pp)
        res[pp] = IS_MAX ? fmaf(-cw, (float)(pp * pp), acc[pp])
                         : fmaf( cw, (float)(pp * pp), acc[pp]);
}

template <bool IS_MAX>
__global__ __launch_bounds__(512, 4) void mscan(const float* __restrict__ in,
                                                float* __restrict__ outT,
                                                const float* __restrict__ cptr,
                                                long in_ks, long in_zs,
                                                long out_ks, long out_zs, int kofs)
{
    __shared__ float lds[64 * LROW];
    const int k = kofs + (int)blockIdx.y;
    const int W = 4 << k;
    const float cw = ldexpf(cptr[0], -(2 + 2 * k));   // c*4/W^2 (pow2-exact scale)
    const int tile = blockIdx.x;                      // 16 tiles: 4x * 4h
    const int x0 = (tile & 3) * 64;
    const int h0 = (tile >> 2) * 64;
    const float* ip = in + (long)k * in_ks + (long)blockIdx.z * in_zs;
    float* op = outT + (long)k * out_ks + (long)blockIdx.z * out_zs;

    const int tid = threadIdx.x;
    const int tx = tid & 63;       // fast-axis column within tile (wave = 64 cols)
    const int ty = tid >> 6;       // 0..7: slow-axis output group
    const int x = x0 + tx;
    const int rowbase = h0 + ty * 8 - W;

    float res[8];
    if (h0 >= W && h0 + 63 + W <= HH - 1)            // block-uniform
        scan_core<IS_MAX, false>(ip, W, cw, x, rowbase, res);
    else
        scan_core<IS_MAX, true >(ip, W, cw, x, rowbase, res);

    // LDS transpose: lds[tx][8*ty + pp]  (stride LROW: b128-aligned rows)
    float* lp = lds + tx * LROW + ty * 8;
    *(float4*)(lp)     = make_float4(res[0], res[1], res[2], res[3]);
    *(float4*)(lp + 4) = make_float4(res[4], res[5], res[6], res[7]);
    __syncthreads();

    // coalesced store of the 64x64 tile: 1024 float4s, 2 per thread.
    // wave stores 4 full 256B rows per instruction.
#pragma unroll
    for (int p = 0; p < 2; ++p) {
        const int f = p * 512 + tid;     // float4 index
        const int r = f >> 4;            // tile x-row 0..63
        const int c4 = f & 15;           // float4 within row
        const float4 vv = *(const float4*)(lds + r * LROW + c4 * 4);
        *(float4*)(op + (long)(x0 + r) * FAST + h0 + c4 * 4) = vv;
    }
}

extern "C" void kernel_launch(void* const* d_in, const int* in_sizes, int n_in,
                              void* d_out, int out_size, void* d_ws, size_t ws_size,
                              hipStream_t stream)
{
    const float* x = (const float*)d_in[0];   // [4,8,256,256] fp32
    const float* c = (const float*)d_in[1];   // scalar se_coef
    float* out = (float*)d_out;               // [4,8,4,256,256] fp32
    float* ws  = (float*)d_ws;

    dim3 b(512);
    if (ws_size >= (size_t)(NS * SLICE) * sizeof(float)) {
        // merged: 4 dispatches, all scales in-grid.
        // Rotation: x -> ws(T1) -> out-as-scratch(T2) -> ws(T3) -> out(final).
        dim3 g(16, NS, BC);
        mscan<true ><<<g, b, 0, stream>>>(x,   ws,  c, 0,     HW, SLICE, HW, 0);
        mscan<true ><<<g, b, 0, stream>>>(ws,  out, c, SLICE, HW, SLICE, HW, 0);
        mscan<false><<<g, b, 0, stream>>>(out, ws,  c, SLICE, HW, SLICE, HW, 0);
        mscan<false><<<g, b, 0, stream>>>(ws,  out, c, SLICE, HW, HW, (long)NS * HW, 0);
    } else {
        // fallback: per-scale ping-pong via one 8.4MB ws slice + out slice k
        dim3 g(16, 1, BC);
        for (int k = 0; k < NS; ++k) {
            float* outk = out + (long)k * HW;
            mscan<true ><<<g, b, 0, stream>>>(x,    ws,   c, 0, HW, 0, HW, k);
            mscan<true ><<<g, b, 0, stream>>>(ws,   outk, c, 0, HW, 0, (long)NS * HW, k);
            mscan<false><<<g, b, 0, stream>>>(outk, ws,   c, 0, (long)NS * HW, 0, HW, k);
            mscan<false><<<g, b, 0, stream>>>(ws,   outk, c, 0, HW, 0, (long)NS * HW, k);
        }
    }
}

// Round 7
// 168.569 us; speedup vs baseline: 1.3938x; 1.0853x over previous
//
#include <hip/hip_runtime.h>

// Multi-scale parabolic morphological closing — vertical-scan formulation,
// LDS-transposed coalesced output, MLP-8 batched tap loads.
// closing_k = ero2d(dil2d(x)), W_k = 4<<k, weight(d) = c*(4/W^2)*d^2.
// All 4 separable passes are vertical scans writing transposed:
//   X -dilV-> T1[w][h] -dilH-> T2[h][w] -eroV-> T3[w][h] -eroH-> OUT[h][w]
// Candidate algebra: v -+ cw*(D-pp)^2 = (v -+ cw*D^2) +- (2cw*D)*pp -+ cw*pp^2.
// Tap constants computed straight from anchors with literal multipliers:
//   q(t) = q_anchor + t*qs_anchor + T(t)*2cw   (T(t)=t(t-1)/2, all exact*cw)
//   s(t) = s_anchor + t*ss
// -> no loop-carried FP chains. Taps processed in chunks of 8 with all 8 loads
// issued before use (R5/R6 bottleneck: MLP=2 + serial chain -> latency-bound,
// VALUBusy 27%). Window masks (head pp<=t, tail pp>=t-2W) are compile-time.

#define HH 256
#define FAST 256
#define BC 32
#define NS 4
#define HW (HH * FAST)
#define SLICE ((long)BC * HW)
#define LROW 68   // LDS row stride (floats)

template <bool IS_MAX, bool CLAMP>
__device__ __forceinline__ void scan_core(const float* __restrict__ img,
                                          int W, float cw, int x, int rowbase,
                                          float res[8])
{
    const float PAD = IS_MAX ? -1e30f : 1e30f;
    const float tw = 2.0f * cw;
    const float ss = IS_MAX ? tw : -tw;              // slope step, sign-folded
    const float q0  = cw * (float)(W * W);           // q at tap 0 (D=-W) and tap 2W (D=+W)
    const float qs0 = cw * (float)(1 - 2 * W);       // cw*(2D+1) at D=-W
    const float qsT = fmaf(tw, (float)W, cw);        // cw*(2W+1) at D=+W
    const float s0  = IS_MAX ? (-tw * (float)W) : (tw * (float)W);
    const float sT  = IS_MAX ? (tw * (float)W) : (-tw * (float)W);

    float acc[8];
#pragma unroll
    for (int pp = 0; pp < 8; ++pp) acc[pp] = PAD;

    const float* pb = img + x;
    auto load1 = [&](int u) -> float {
        const int row = rowbase + u;
        if (!CLAMP) return pb[row * FAST];
        const int rc = min(max(row, 0), HH - 1);     // always-safe address
        const float t = pb[rc * FAST];
        return (row == rc) ? t : PAD;
    };

    float v[8];

    // ---- head: taps t=0..7, tap t valid for pp <= t ----
#pragma unroll
    for (int j = 0; j < 8; ++j) v[j] = load1(j);
#pragma unroll
    for (int j = 0; j < 8; ++j) {
        const float qj = fmaf((float)((j * (j - 1)) / 2), tw, fmaf((float)j, qs0, q0));
        const float sj = fmaf((float)j, ss, s0);
        const float vp = IS_MAX ? v[j] - qj : v[j] + qj;
#pragma unroll
        for (int pp = 0; pp < 8; ++pp)
            if (pp <= j) {
                const float cnd = fmaf(sj, (float)pp, vp);
                acc[pp] = IS_MAX ? fmaxf(acc[pp], cnd) : fminf(acc[pp], cnd);
            }
    }

    // ---- middle: taps t=8..2W-1 in chunks of 8; nch = W/4-1 (0,1,3,7), guarded unroll
    const int nch = (W >> 2) - 1;
#pragma unroll
    for (int m = 0; m < 7; ++m) {
        if (m < nch) {                               // wave-uniform guard
#pragma unroll
            for (int j = 0; j < 8; ++j) v[j] = load1(8 + 8 * m + j);
#pragma unroll
            for (int j = 0; j < 8; j += 2) {
                const int t0 = 8 + 8 * m + j, t1 = t0 + 1;
                const float qa = fmaf((float)((t0 * (t0 - 1)) / 2), tw,
                                      fmaf((float)t0, qs0, q0));
                const float qb = fmaf((float)((t1 * (t1 - 1)) / 2), tw,
                                      fmaf((float)t1, qs0, q0));
                const float sa = fmaf((float)t0, ss, s0);
                const float sb = fmaf((float)t1, ss, s0);
                const float va = IS_MAX ? v[j]     - qa : v[j]     + qa;
                const float vb = IS_MAX ? v[j + 1] - qb : v[j + 1] + qb;
#pragma unroll
                for (int pp = 0; pp < 8; ++pp) {
                    const float ca = fmaf(sa, (float)pp, va);
                    const float cb = fmaf(sb, (float)pp, vb);
                    acc[pp] = IS_MAX ? fmaxf(acc[pp], fmaxf(ca, cb))
                                     : fminf(acc[pp], fminf(ca, cb));
                }
            }
        }
    }

    // ---- tail: taps t=2W+j, j=0..7, valid for pp >= j ----
#pragma unroll
    for (int j = 0; j < 8; ++j) v[j] = load1(2 * W + j);
#pragma unroll
    for (int j = 0; j < 8; ++j) {
        const float qj = fmaf((float)((j * (j - 1)) / 2), tw, fmaf((float)j, qsT, q0));
        const float sj = fmaf((float)j, ss, sT);
        const float vp = IS_MAX ? v[j] - qj : v[j] + qj;
#pragma unroll
        for (int pp = 0; pp < 8; ++pp)
            if (pp >= j) {
                const float cnd = fmaf(sj, (float)pp, vp);
                acc[pp] = IS_MAX ? fmaxf(acc[pp], cnd) : fminf(acc[pp], cnd);
            }
    }

    // fold -+cw*pp^2
#pragma unroll
    for (int pp = 0; pp < 8; ++pp)
        res[pp] = IS_MAX ? fmaf(-cw, (float)(pp * pp), acc[pp])
                         : fmaf( cw, (float)(pp * pp), acc[pp]);
}

template <bool IS_MAX>
__global__ __launch_bounds__(512, 4) void mscan(const float* __restrict__ in,
                                                float* __restrict__ outT,
                                                const float* __restrict__ cptr,
                                                long in_ks, long in_zs,
                                                long out_ks, long out_zs, int kofs)
{
    __shared__ float lds[64 * LROW];
    const int k = kofs + (int)blockIdx.y;
    const int W = 4 << k;
    const float cw = ldexpf(cptr[0], -(2 + 2 * k));  // c*4/W^2, pow2-exact
    const int tile = blockIdx.x;                     // 16 tiles: 4x * 4h
    const int x0 = (tile & 3) * 64;
    const int h0 = (tile >> 2) * 64;
    const float* ip = in + (long)k * in_ks + (long)blockIdx.z * in_zs;
    float* op = outT + (long)k * out_ks + (long)blockIdx.z * out_zs;

    const int tid = threadIdx.x;
    const int tx = tid & 63;       // fast-axis column (wave = 64 consecutive cols)
    const int ty = tid >> 6;       // 0..7, uniform per wave
    const int x = x0 + tx;
    const int rowbase = h0 + ty * 8 - W;

    float res[8];
    if (rowbase >= 0 && rowbase + 2 * W + 7 < HH)    // wave-uniform branch
        scan_core<IS_MAX, false>(ip, W, cw, x, rowbase, res);
    else
        scan_core<IS_MAX, true >(ip, W, cw, x, rowbase, res);

    // LDS transpose: lds[tx][8*ty + pp]
    float* lp = lds + tx * LROW + ty * 8;
    *(float4*)(lp)     = make_float4(res[0], res[1], res[2], res[3]);
    *(float4*)(lp + 4) = make_float4(res[4], res[5], res[6], res[7]);
    __syncthreads();

    // coalesced store of the 64x64 transposed tile: 2 float4s per thread
#pragma unroll
    for (int p = 0; p < 2; ++p) {
        const int f = p * 512 + tid;
        const int r = f >> 4;            // tile fast-row 0..63
        const int c4 = f & 15;           // float4 within row
        const float4 vv = *(const float4*)(lds + r * LROW + c4 * 4);
        *(float4*)(op + (long)(x0 + r) * FAST + h0 + c4 * 4) = vv;
    }
}

extern "C" void kernel_launch(void* const* d_in, const int* in_sizes, int n_in,
                              void* d_out, int out_size, void* d_ws, size_t ws_size,
                              hipStream_t stream)
{
    const float* x = (const float*)d_in[0];   // [4,8,256,256] fp32
    const float* c = (const float*)d_in[1];   // scalar se_coef
    float* out = (float*)d_out;               // [4,8,4,256,256] fp32
    float* ws  = (float*)d_ws;

    dim3 b(512);
    if (ws_size >= (size_t)(NS * SLICE) * sizeof(float)) {
        // merged: 4 dispatches, all scales in-grid.
        // Rotation: x -> ws(T1) -> out-as-scratch(T2) -> ws(T3) -> out(final).
        dim3 g(16, NS, BC);
        mscan<true ><<<g, b, 0, stream>>>(x,   ws,  c, 0,     HW, SLICE, HW, 0);
        mscan<true ><<<g, b, 0, stream>>>(ws,  out, c, SLICE, HW, SLICE, HW, 0);
        mscan<false><<<g, b, 0, stream>>>(out, ws,  c, SLICE, HW, SLICE, HW, 0);
        mscan<false><<<g, b, 0, stream>>>(ws,  out, c, SLICE, HW, HW, (long)NS * HW, 0);
    } else {
        // fallback: per-scale ping-pong via one 8.4MB ws slice + out slice k
        dim3 g(16, 1, BC);
        for (int k = 0; k < NS; ++k) {
            float* outk = out + (long)k * HW;
            mscan<true ><<<g, b, 0, stream>>>(x,    ws,   c, 0, HW, 0, HW, k);
            mscan<true ><<<g, b, 0, stream>>>(ws,   outk, c, 0, HW, 0, (long)NS * HW, k);
            mscan<false><<<g, b, 0, stream>>>(outk, ws,   c, 0, (long)NS * HW, 0, HW, k);
            mscan<false><<<g, b, 0, stream>>>(ws,   outk, c, 0, HW, 0, (long)NS * HW, k);
        }
    }
}